// Round 1
// baseline (126.212 us; speedup 1.0000x reference)
//
#include <hip/hip_runtime.h>
#include <hip/hip_bf16.h>

typedef __hip_bfloat16 bf16;
typedef __attribute__((ext_vector_type(8))) short short8;
typedef __attribute__((ext_vector_type(4))) float floatx4;

#define B_   4
#define C_   256
#define CQ_  32
#define M_   8
#define MID_ 16
#define H_   56
#define W_   56
#define HW_  3136
#define K_   7

__device__ __forceinline__ unsigned short f2bf(float f) {
    __hip_bfloat16 h = __float2bfloat16(f);
    return *(unsigned short*)&h;
}

// ---------------- setup: weight converts + geometry prior (merged) ----------------
// blocks 0-63: wkqb[64][256] (rows 0-31 w_k, 32-63 w_q)
// blocks 64-319: wfp[ch][kk], kk = cq*8+m permuted from w_f[ch][m*32+cq]
// blocks 320-326: gpk[cq][i][j]
__global__ void setup_kernel(const float* __restrict__ wk, const float* __restrict__ wq,
                             const float* __restrict__ wf,
                             const float* __restrict__ wg1, const float* __restrict__ bg1,
                             const float* __restrict__ wg2, const float* __restrict__ bg2,
                             bf16* __restrict__ wkqb, bf16* __restrict__ wfp,
                             float* __restrict__ gpk) {
    int bid = blockIdx.x, t = threadIdx.x;
    if (bid < 64) {
        int i = bid * 256 + t;
        wkqb[i] = __float2bfloat16(i < 8192 ? wk[i] : wq[i - 8192]);
    } else if (bid < 320) {
        int j  = (bid - 64) * 256 + t;
        int ch = j >> 8, kk = j & 255;
        int cq = kk >> 3, m = kk & 7;
        wfp[j] = __float2bfloat16(wf[ch * 256 + m * 32 + cq]);
    } else {
        int idx = (bid - 320) * 256 + t;
        if (idx >= CQ_ * 49) return;
        int cq = idx / 49, ij = idx % 49;
        int i = ij / 7, j = ij % 7;
        float xp = (float)(j - 3);
        float yp = (float)(3 - i);
        float acc = bg2[cq];
        #pragma unroll
        for (int o = 0; o < MID_; o++) {
            float g1 = wg1[o * 2 + 0] * xp + wg1[o * 2 + 1] * yp + bg1[o];
            acc += wg2[cq * MID_ + o] * fmaxf(g1, 0.0f);
        }
        gpk[idx] = acc;
    }
}

// ---------------- km/qm via MFMA, fp32 float4 staging + swizzled LDS transpose ----------------
// grid (HW/32, B); block 256 = 4 waves. Block: 64 rows (32 km + 32 qm) x 32 px.
__global__ void __launch_bounds__(256) kq_mfma(const float* __restrict__ x,
                                               const bf16* __restrict__ wkqb,
                                               const float* __restrict__ b_k,
                                               const float* __restrict__ b_q,
                                               float* __restrict__ km, float* __restrict__ qm) {
    __shared__ short lt[32 * 264];   // [px][c], 16B chunks swizzled by ((c8 + (px>>2)) & 31)
    int hw0 = blockIdx.x * 32;
    int b   = blockIdx.y;
    int t   = threadIdx.x;

    {   // stage x[b][c][hw0..hw0+31] -> bf16 lt; coalesced float4 global reads
        int pq = t & 7, cb = t >> 3;            // px-quad, c-pair index
        const float* xb = x + (size_t)b * C_ * HW_ + hw0 + pq * 4;
        #pragma unroll
        for (int ii = 0; ii < 4; ii++) {
            int c = ii * 64 + cb * 2;
            floatx4 fa = *(const floatx4*)(xb + (size_t)c * HW_);
            floatx4 fb = *(const floatx4*)(xb + (size_t)(c + 1) * HW_);
            int c8 = c >> 3, sub = c & 7;
            #pragma unroll
            for (int u = 0; u < 4; u++) {
                int px = pq * 4 + u;
                unsigned uu = (unsigned)f2bf(fa[u]) | ((unsigned)f2bf(fb[u]) << 16);
                int off = px * 264 + ((c8 + (px >> 2)) & 31) * 8 + sub;
                *(unsigned*)&lt[off] = uu;
            }
        }
    }
    __syncthreads();

    int wave = t >> 6, lane = t & 63, quad = lane >> 4, nl = lane & 15;
    int m0 = wave * 16;
    const short* arow = (const short*)wkqb + (m0 + nl) * C_ + quad * 8;
    short8 af[8];
    #pragma unroll
    for (int k0 = 0; k0 < 8; k0++) af[k0] = *(const short8*)(arow + k0 * 32);

    floatx4 acc[2];
    #pragma unroll
    for (int nt = 0; nt < 2; nt++) acc[nt] = (floatx4){0.f, 0.f, 0.f, 0.f};

    #pragma unroll
    for (int nt = 0; nt < 2; nt++) {
        int px = nt * 16 + nl;
        int prow = px * 264, sw = px >> 2;
        #pragma unroll
        for (int k0 = 0; k0 < 8; k0++) {
            int c8 = k0 * 4 + quad;
            short8 bf = *(const short8*)&lt[prow + ((c8 + sw) & 31) * 8];
            acc[nt] = __builtin_amdgcn_mfma_f32_16x16x32_bf16(af[k0], bf, acc[nt], 0, 0, 0);
        }
    }

    #pragma unroll
    for (int r = 0; r < 4; r++) {
        int ch = m0 + quad * 4 + r;       // 0..63
        bool isK = (ch < 32);
        int c = isK ? ch : ch - 32;
        float bias = isK ? b_k[c] : b_q[c];
        float* dst = (isK ? km : qm) + ((size_t)b * CQ_ + c) * HW_ + hw0 + nl;
        dst[0]  = acc[0][r] + bias;
        dst[16] = acc[1][r] + bias;
    }
}

// ---------------- core: softmax + aggregation, float4 LDS, permuted bf16 output ----------------
// grid (7 stripes, CQ, B); block 448 = 8 rows x 56 cols.
// pre_t[b][px][kk], kk = cq*8 + m  (channel = m*32+cq) -> one short8 store/thread.
__global__ void __launch_bounds__(448) core_kernel(const float* __restrict__ x,
                                                   const float* __restrict__ km,
                                                   const float* __restrict__ qm,
                                                   const float* __restrict__ gpk,
                                                   bf16* __restrict__ pret) {
    __shared__ float   kms[14 * 62];
    __shared__ floatx4 xs4[2][14 * 62];   // [g][halo pos]: g=0 -> m 0-3, g=1 -> m 4-7

    int ht = blockIdx.x, cq = blockIdx.y, b = blockIdx.z;
    int h0 = ht * 8, t = threadIdx.x;

    const float* kmc = km + ((size_t)b * CQ_ + cq) * HW_;
    for (int idx = t; idx < 868; idx += 448) {
        int rr = idx / 62, cc = idx % 62;
        int gh = h0 + rr - 3, gw = cc - 3;
        bool in = ((unsigned)gh < 56u) && ((unsigned)gw < 56u);
        int o = gh * 56 + gw;
        kms[idx] = in ? kmc[o] : 0.f;
        #pragma unroll
        for (int g = 0; g < 2; g++) {
            floatx4 v;
            #pragma unroll
            for (int mm = 0; mm < 4; mm++) {
                const float* xc = x + ((size_t)b * C_ + (g * 4 + mm) * CQ_ + cq) * HW_;
                v[mm] = in ? xc[o] : 0.f;
            }
            xs4[g][idx] = v;
        }
    }
    __syncthreads();

    int r = t / 56, w = t % 56, h = h0 + r;
    float q = qm[((size_t)b * CQ_ + cq) * HW_ + h * 56 + w];
    const float* gp = gpk + cq * 49;      // wave-uniform -> scalar loads

    float ck[49];
    #pragma unroll
    for (int i = 0; i < 7; i++) {
        int base = (r + i) * 62 + w;
        float v[7], s = 0.f;
        #pragma unroll
        for (int j = 0; j < 7; j++) {     // logits bounded (~|10|): exp safe without max-sub
            v[j] = __expf(kms[base + j] * q + gp[i * 7 + j]);
            s += v[j];
        }
        float inv = 1.0f / s;
        #pragma unroll
        for (int j = 0; j < 7; j++) ck[i * 7 + j] = v[j] * inv;
    }

    floatx4 a0 = {0.f, 0.f, 0.f, 0.f}, a1 = {0.f, 0.f, 0.f, 0.f};
    #pragma unroll
    for (int i = 0; i < 7; i++) {
        int base = (r + i) * 62 + w;
        #pragma unroll
        for (int j = 0; j < 7; j++) {
            float c = ck[i * 7 + j];
            a0 += c * xs4[0][base + j];   // ds_read_b128, 2-way (free)
            a1 += c * xs4[1][base + j];
        }
    }

    short8 o8;
    #pragma unroll
    for (int mm = 0; mm < 4; mm++) {
        o8[mm]     = (short)f2bf(a0[mm]);
        o8[mm + 4] = (short)f2bf(a1[mm]);
    }
    *(short8*)((short*)pret + ((size_t)b * HW_ + h * 56 + w) * C_ + cq * 8) = o8;
}

// ---------------- final 1x1 conv via MFMA, LDS-free (B-frags direct from pre_t) ----------------
// grid (HW/64, 4 ch-blocks, B); block 256 = 4 waves; wave = 16 ch x 64 px.
__global__ void __launch_bounds__(256) fconv_mfma(const bf16* __restrict__ pret,
                                                  const bf16* __restrict__ wfp,
                                                  const float* __restrict__ b_f,
                                                  float* __restrict__ out) {
    int hw0 = blockIdx.x * 64;
    int bm  = blockIdx.y;
    int b   = blockIdx.z;
    int t   = threadIdx.x, wave = t >> 6, lane = t & 63, quad = lane >> 4, nl = lane & 15;
    int m0  = bm * 64 + wave * 16;

    const short* arow = (const short*)wfp + (m0 + nl) * C_ + quad * 8;
    short8 af[8];
    #pragma unroll
    for (int k0 = 0; k0 < 8; k0++) af[k0] = *(const short8*)(arow + k0 * 32);

    floatx4 acc[4];
    #pragma unroll
    for (int nt = 0; nt < 4; nt++) acc[nt] = (floatx4){0.f, 0.f, 0.f, 0.f};

    const short* pb = (const short*)pret + ((size_t)b * HW_ + hw0 + nl) * C_ + quad * 8;
    #pragma unroll
    for (int nt = 0; nt < 4; nt++) {
        const short* bp = pb + (size_t)nt * 16 * C_;
        #pragma unroll
        for (int k0 = 0; k0 < 8; k0++)
            acc[nt] = __builtin_amdgcn_mfma_f32_16x16x32_bf16(af[k0], *(const short8*)(bp + k0 * 32),
                                                              acc[nt], 0, 0, 0);
    }

    #pragma unroll
    for (int r = 0; r < 4; r++) {
        int ch = m0 + quad * 4 + r;
        float bias = b_f[ch];
        float* dst = out + ((size_t)b * C_ + ch) * HW_ + hw0 + nl;
        #pragma unroll
        for (int nt = 0; nt < 4; nt++)
            dst[nt * 16] = acc[nt][r] + bias;
    }
}

extern "C" void kernel_launch(void* const* d_in, const int* in_sizes, int n_in,
                              void* d_out, int out_size, void* d_ws, size_t ws_size,
                              hipStream_t stream) {
    const float* x    = (const float*)d_in[0];
    const float* w_k  = (const float*)d_in[1];
    const float* b_k  = (const float*)d_in[2];
    const float* w_q  = (const float*)d_in[3];
    const float* b_q  = (const float*)d_in[4];
    const float* w_g1 = (const float*)d_in[5];
    const float* b_g1 = (const float*)d_in[6];
    const float* w_g2 = (const float*)d_in[7];
    const float* b_g2 = (const float*)d_in[8];
    const float* w_f  = (const float*)d_in[9];
    const float* b_f  = (const float*)d_in[10];
    float* out = (float*)d_out;

    float* ws   = (float*)d_ws;
    float* km   = ws;                              // 401408 f32
    float* qm   = km + (size_t)B_ * CQ_ * HW_;     // 401408 f32
    float* gpk  = qm + (size_t)B_ * CQ_ * HW_;     // 1568 f32
    bf16*  wkqb = (bf16*)(gpk + CQ_ * 49);         // 64*256 bf16
    bf16*  wfp  = wkqb + 64 * C_;                  // 256*256 bf16 (K-permuted w_f)
    bf16*  pret = wfp + C_ * C_;                   // B*HW*256 bf16, [b][px][kk]

    setup_kernel<<<dim3(327), 256, 0, stream>>>(w_k, w_q, w_f, w_g1, b_g1, w_g2, b_g2,
                                                wkqb, wfp, gpk);
    kq_mfma<<<dim3(HW_ / 32, B_), 256, 0, stream>>>(x, wkqb, b_k, b_q, km, qm);
    core_kernel<<<dim3(7, CQ_, B_), 448, 0, stream>>>(x, km, qm, gpk, pret);
    fconv_mfma<<<dim3(HW_ / 64, C_ / 64, B_), 256, 0, stream>>>(pret, wfp, b_f, out);
}

// Round 2
// 125.807 us; speedup vs baseline: 1.0032x; 1.0032x over previous
//
#include <hip/hip_runtime.h>
#include <hip/hip_bf16.h>

typedef __hip_bfloat16 bf16;
typedef __attribute__((ext_vector_type(8))) short short8;
typedef __attribute__((ext_vector_type(4))) float floatx4;

#define B_   4
#define C_   256
#define CQ_  32
#define M_   8
#define MID_ 16
#define H_   56
#define W_   56
#define HW_  3136
#define K_   7

__device__ __forceinline__ unsigned short f2bf(float f) {
    __hip_bfloat16 h = __float2bfloat16(f);
    return *(unsigned short*)&h;
}

// ---------------- setup: weight converts + geometry prior (merged) ----------------
__global__ void setup_kernel(const float* __restrict__ wk, const float* __restrict__ wq,
                             const float* __restrict__ wf,
                             const float* __restrict__ wg1, const float* __restrict__ bg1,
                             const float* __restrict__ wg2, const float* __restrict__ bg2,
                             bf16* __restrict__ wkqb, bf16* __restrict__ wfp,
                             float* __restrict__ gpk) {
    int bid = blockIdx.x, t = threadIdx.x;
    if (bid < 64) {
        int i = bid * 256 + t;
        wkqb[i] = __float2bfloat16(i < 8192 ? wk[i] : wq[i - 8192]);
    } else if (bid < 320) {
        int j  = (bid - 64) * 256 + t;
        int ch = j >> 8, kk = j & 255;
        int cq = kk >> 3, m = kk & 7;
        wfp[j] = __float2bfloat16(wf[ch * 256 + m * 32 + cq]);
    } else {
        int idx = (bid - 320) * 256 + t;
        if (idx >= CQ_ * 49) return;
        int cq = idx / 49, ij = idx % 49;
        int i = ij / 7, j = ij % 7;
        float xp = (float)(j - 3);
        float yp = (float)(3 - i);
        float acc = bg2[cq];
        #pragma unroll
        for (int o = 0; o < MID_; o++) {
            float g1 = wg1[o * 2 + 0] * xp + wg1[o * 2 + 1] * yp + bg1[o];
            acc += wg2[cq * MID_ + o] * fmaxf(g1, 0.0f);
        }
        gpk[idx] = acc;
    }
}

// ---------------- km/qm via MFMA, fp32 float4 staging + swizzled LDS transpose ----------------
__global__ void __launch_bounds__(256) kq_mfma(const float* __restrict__ x,
                                               const bf16* __restrict__ wkqb,
                                               const float* __restrict__ b_k,
                                               const float* __restrict__ b_q,
                                               float* __restrict__ km, float* __restrict__ qm) {
    __shared__ short lt[32 * 264];
    int hw0 = blockIdx.x * 32;
    int b   = blockIdx.y;
    int t   = threadIdx.x;

    {
        int pq = t & 7, cb = t >> 3;
        const float* xb = x + (size_t)b * C_ * HW_ + hw0 + pq * 4;
        #pragma unroll
        for (int ii = 0; ii < 4; ii++) {
            int c = ii * 64 + cb * 2;
            floatx4 fa = *(const floatx4*)(xb + (size_t)c * HW_);
            floatx4 fb = *(const floatx4*)(xb + (size_t)(c + 1) * HW_);
            int c8 = c >> 3, sub = c & 7;
            #pragma unroll
            for (int u = 0; u < 4; u++) {
                int px = pq * 4 + u;
                unsigned uu = (unsigned)f2bf(fa[u]) | ((unsigned)f2bf(fb[u]) << 16);
                int off = px * 264 + ((c8 + (px >> 2)) & 31) * 8 + sub;
                *(unsigned*)&lt[off] = uu;
            }
        }
    }
    __syncthreads();

    int wave = t >> 6, lane = t & 63, quad = lane >> 4, nl = lane & 15;
    int m0 = wave * 16;
    const short* arow = (const short*)wkqb + (m0 + nl) * C_ + quad * 8;
    short8 af[8];
    #pragma unroll
    for (int k0 = 0; k0 < 8; k0++) af[k0] = *(const short8*)(arow + k0 * 32);

    floatx4 acc[2];
    #pragma unroll
    for (int nt = 0; nt < 2; nt++) acc[nt] = (floatx4){0.f, 0.f, 0.f, 0.f};

    #pragma unroll
    for (int nt = 0; nt < 2; nt++) {
        int px = nt * 16 + nl;
        int prow = px * 264, sw = px >> 2;
        #pragma unroll
        for (int k0 = 0; k0 < 8; k0++) {
            int c8 = k0 * 4 + quad;
            short8 bf = *(const short8*)&lt[prow + ((c8 + sw) & 31) * 8];
            acc[nt] = __builtin_amdgcn_mfma_f32_16x16x32_bf16(af[k0], bf, acc[nt], 0, 0, 0);
        }
    }

    #pragma unroll
    for (int r = 0; r < 4; r++) {
        int ch = m0 + quad * 4 + r;
        bool isK = (ch < 32);
        int c = isK ? ch : ch - 32;
        float bias = isK ? b_k[c] : b_q[c];
        float* dst = (isK ? km : qm) + ((size_t)b * CQ_ + c) * HW_ + hw0 + nl;
        dst[0]  = acc[0][r] + bias;
        dst[16] = acc[1][r] + bias;
    }
}

// ---------------- core: row-pair softmax + aggregation ----------------
// grid (7 stripes, CQ, B); block 256: t<224 = 4 row-pairs x 56 cols, 2 outputs/thread.
// Each halo row hr (0..7) is read from LDS ONCE and feeds output A (i=hr) and
// output B (i=hr-1): xs4 reads 98->56 per output, kms 49->28. Same FP order as before.
__global__ void __launch_bounds__(256) core_kernel(const float* __restrict__ x,
                                                   const float* __restrict__ km,
                                                   const float* __restrict__ qm,
                                                   const float* __restrict__ gpk,
                                                   bf16* __restrict__ pret) {
    __shared__ float   kms[14 * 62];
    __shared__ floatx4 xs4[2][14 * 62];   // [g][halo pos]: g=0 -> m 0-3, g=1 -> m 4-7

    int ht = blockIdx.x, cq = blockIdx.y, b = blockIdx.z;
    int h0 = ht * 8, t = threadIdx.x;

    const float* kmc = km + ((size_t)b * CQ_ + cq) * HW_;
    for (int idx = t; idx < 868; idx += 256) {
        int rr = idx / 62, cc = idx % 62;
        int gh = h0 + rr - 3, gw = cc - 3;
        bool in = ((unsigned)gh < 56u) && ((unsigned)gw < 56u);
        int o = gh * 56 + gw;
        kms[idx] = in ? kmc[o] : 0.f;
        #pragma unroll
        for (int g = 0; g < 2; g++) {
            floatx4 v;
            #pragma unroll
            for (int mm = 0; mm < 4; mm++) {
                const float* xc = x + ((size_t)b * C_ + (g * 4 + mm) * CQ_ + cq) * HW_;
                v[mm] = in ? xc[o] : 0.f;
            }
            xs4[g][idx] = v;
        }
    }
    __syncthreads();

    if (t >= 224) return;
    int rp = t / 56, w = t % 56;
    int hA = h0 + rp * 2, hB = hA + 1;

    const float* qmc = qm + ((size_t)b * CQ_ + cq) * HW_;
    float qA = qmc[hA * 56 + w];
    float qB = qmc[hB * 56 + w];
    const float* gp = gpk + cq * 49;      // wave-uniform -> scalar loads

    floatx4 aA0 = {0.f,0.f,0.f,0.f}, aA1 = {0.f,0.f,0.f,0.f};
    floatx4 aB0 = {0.f,0.f,0.f,0.f}, aB1 = {0.f,0.f,0.f,0.f};

    #pragma unroll
    for (int hr = 0; hr < 8; hr++) {
        int base = (rp * 2 + hr) * 62 + w;
        float kv[7];
        #pragma unroll
        for (int j = 0; j < 7; j++) kv[j] = kms[base + j];

        float wA[7], wB[7];
        if (hr < 7) {                     // output A, window row i = hr
            float s = 0.f;
            #pragma unroll
            for (int j = 0; j < 7; j++) {
                wA[j] = __expf(kv[j] * qA + gp[hr * 7 + j]);
                s += wA[j];
            }
            float inv = 1.0f / s;
            #pragma unroll
            for (int j = 0; j < 7; j++) wA[j] *= inv;
        }
        if (hr >= 1) {                    // output B, window row i = hr-1
            float s = 0.f;
            #pragma unroll
            for (int j = 0; j < 7; j++) {
                wB[j] = __expf(kv[j] * qB + gp[(hr - 1) * 7 + j]);
                s += wB[j];
            }
            float inv = 1.0f / s;
            #pragma unroll
            for (int j = 0; j < 7; j++) wB[j] *= inv;
        }

        #pragma unroll
        for (int j = 0; j < 7; j++) {
            floatx4 x0 = xs4[0][base + j];  // ds_read_b128, shared by A and B
            floatx4 x1 = xs4[1][base + j];
            if (hr < 7)  { aA0 += wA[j] * x0; aA1 += wA[j] * x1; }
            if (hr >= 1) { aB0 += wB[j] * x0; aB1 += wB[j] * x1; }
        }
    }

    short8 o8;
    #pragma unroll
    for (int mm = 0; mm < 4; mm++) {
        o8[mm]     = (short)f2bf(aA0[mm]);
        o8[mm + 4] = (short)f2bf(aA1[mm]);
    }
    *(short8*)((short*)pret + ((size_t)b * HW_ + hA * 56 + w) * C_ + cq * 8) = o8;

    #pragma unroll
    for (int mm = 0; mm < 4; mm++) {
        o8[mm]     = (short)f2bf(aB0[mm]);
        o8[mm + 4] = (short)f2bf(aB1[mm]);
    }
    *(short8*)((short*)pret + ((size_t)b * HW_ + hB * 56 + w) * C_ + cq * 8) = o8;
}

// ---------------- final 1x1 conv via MFMA, LDS-free ----------------
__global__ void __launch_bounds__(256) fconv_mfma(const bf16* __restrict__ pret,
                                                  const bf16* __restrict__ wfp,
                                                  const float* __restrict__ b_f,
                                                  float* __restrict__ out) {
    int hw0 = blockIdx.x * 64;
    int bm  = blockIdx.y;
    int b   = blockIdx.z;
    int t   = threadIdx.x, wave = t >> 6, lane = t & 63, quad = lane >> 4, nl = lane & 15;
    int m0  = bm * 64 + wave * 16;

    const short* arow = (const short*)wfp + (m0 + nl) * C_ + quad * 8;
    short8 af[8];
    #pragma unroll
    for (int k0 = 0; k0 < 8; k0++) af[k0] = *(const short8*)(arow + k0 * 32);

    floatx4 acc[4];
    #pragma unroll
    for (int nt = 0; nt < 4; nt++) acc[nt] = (floatx4){0.f, 0.f, 0.f, 0.f};

    const short* pb = (const short*)pret + ((size_t)b * HW_ + hw0 + nl) * C_ + quad * 8;
    #pragma unroll
    for (int nt = 0; nt < 4; nt++) {
        const short* bp = pb + (size_t)nt * 16 * C_;
        #pragma unroll
        for (int k0 = 0; k0 < 8; k0++)
            acc[nt] = __builtin_amdgcn_mfma_f32_16x16x32_bf16(af[k0], *(const short8*)(bp + k0 * 32),
                                                              acc[nt], 0, 0, 0);
    }

    #pragma unroll
    for (int r = 0; r < 4; r++) {
        int ch = m0 + quad * 4 + r;
        float bias = b_f[ch];
        float* dst = out + ((size_t)b * C_ + ch) * HW_ + hw0 + nl;
        #pragma unroll
        for (int nt = 0; nt < 4; nt++)
            dst[nt * 16] = acc[nt][r] + bias;
    }
}

extern "C" void kernel_launch(void* const* d_in, const int* in_sizes, int n_in,
                              void* d_out, int out_size, void* d_ws, size_t ws_size,
                              hipStream_t stream) {
    const float* x    = (const float*)d_in[0];
    const float* w_k  = (const float*)d_in[1];
    const float* b_k  = (const float*)d_in[2];
    const float* w_q  = (const float*)d_in[3];
    const float* b_q  = (const float*)d_in[4];
    const float* w_g1 = (const float*)d_in[5];
    const float* b_g1 = (const float*)d_in[6];
    const float* w_g2 = (const float*)d_in[7];
    const float* b_g2 = (const float*)d_in[8];
    const float* w_f  = (const float*)d_in[9];
    const float* b_f  = (const float*)d_in[10];
    float* out = (float*)d_out;

    float* ws   = (float*)d_ws;
    float* km   = ws;                              // 401408 f32
    float* qm   = km + (size_t)B_ * CQ_ * HW_;     // 401408 f32
    float* gpk  = qm + (size_t)B_ * CQ_ * HW_;     // 1568 f32
    bf16*  wkqb = (bf16*)(gpk + CQ_ * 49);         // 64*256 bf16
    bf16*  wfp  = wkqb + 64 * C_;                  // 256*256 bf16 (K-permuted w_f)
    bf16*  pret = wfp + C_ * C_;                   // B*HW*256 bf16, [b][px][kk]

    setup_kernel<<<dim3(327), 256, 0, stream>>>(w_k, w_q, w_f, w_g1, b_g1, w_g2, b_g2,
                                                wkqb, wfp, gpk);
    kq_mfma<<<dim3(HW_ / 32, B_), 256, 0, stream>>>(x, wkqb, b_k, b_q, km, qm);
    core_kernel<<<dim3(7, CQ_, B_), 256, 0, stream>>>(x, km, qm, gpk, pret);
    fconv_mfma<<<dim3(HW_ / 64, C_ / 64, B_), 256, 0, stream>>>(pret, wfp, b_f, out);
}